// Round 14
// baseline (152.444 us; speedup 1.0000x reference)
//
#include <hip/hip_runtime.h>
#include <hip/hip_bf16.h>

#define NB 2
#define SEQ 2048
#define DM 384
#define NH 8
#define HD 48
#define QKVN 1152
#define BH (NB*NH)

typedef __hip_bfloat16 bf16;
typedef __attribute__((ext_vector_type(8))) short short8;
typedef __attribute__((ext_vector_type(4))) float float4v;

static __device__ __forceinline__ float bf2f(bf16 v){ return __bfloat162float(v); }
static __device__ __forceinline__ float ldin(const void* p, size_t i, int isf){
    return isf ? ((const float*)p)[i] : bf2f(((const bf16*)p)[i]);
}
// fp32 -> bf16 bits, RNE
static __device__ __forceinline__ short f2b(float f){
    union { float f; unsigned u; } a; a.f = f;
    unsigned r = a.u + 0x7FFFu + ((a.u >> 16) & 1u);
    return (short)(r >> 16);
}
// packed fp32x2 -> bf16x2 (v_cvt_pk_bf16_f32)
static __device__ __forceinline__ unsigned pk2(float a, float b){
    union { __hip_bfloat162 h; unsigned u; } r;
    r.h = __float22bfloat162_rn(float2{a, b});
    return r.u;
}
static __device__ __forceinline__ float bflo(unsigned u){
    union { unsigned u; float f; } a; a.u = u << 16; return a.f;
}
static __device__ __forceinline__ float bfhi(unsigned u){
    union { unsigned u; float f; } a; a.u = u & 0xFFFF0000u; return a.f;
}
// short4 (int2) -> short8 with zero upper half (k-relabel trick for d=48 / j=16 chunks)
static __device__ __forceinline__ short8 s4z(int2 v){
    union { int2 i; short s[4]; } u; u.i = v;
    short8 r = {u.s[0], u.s[1], u.s[2], u.s[3], 0, 0, 0, 0};
    return r;
}
static __device__ __forceinline__ short8 u2z(unsigned a, unsigned b){
    union { unsigned u[2]; short s[4]; } u0; u0.u[0] = a; u0.u[1] = b;
    short8 r = {u0.s[0], u0.s[1], u0.s[2], u0.s[3], 0, 0, 0, 0};
    return r;
}
// per-block input dtype probe (0 = bf16, 1 = fp32); wave-uniform
static __device__ __forceinline__ int detect_isf(const void* x){
    const unsigned short* xb = (const unsigned short*)x;
    int l = threadIdx.x & 63;
    union { unsigned u; float f; } a; a.u = ((unsigned)xb[2*l]) << 16;
    float ab = fabsf(a.f);
    int good = (a.f == 0.0f) || (ab > 9.765625e-4f && ab < 1024.0f);
    unsigned long long m = __ballot(good);
    return (__popcll(m) >= 32) ? 0 : 1;
}

// ---------------- K_prep
// sections: [0,512) dist (i-split x2) | [512,1280) xb | [1280,1712) WqT | [1712,1856) WoT | [1856,1863) misc
// dist8 layout: [b][jg(128)][i(2048)][16 jj] bf16
__global__ __launch_bounds__(256) void k_prep(const void* __restrict__ x,
    const void* __restrict__ coords,
    const void* __restrict__ Wqkv, const void* __restrict__ Wout,
    const void* __restrict__ bqkv, const void* __restrict__ bout,
    const void* __restrict__ Wdist, const void* __restrict__ bdist,
    short* __restrict__ dist8, short* __restrict__ xb,
    short* __restrict__ WqT, short* __restrict__ WoT,
    float* __restrict__ bqf, float* __restrict__ bof,
    float* __restrict__ wdf, float* __restrict__ bdf)
{
    const int isf = detect_isf(x);
    const int t = threadIdx.x;
    const int b = blockIdx.x;
    if (b < 512) {
        const int bb = b >> 8;               // batch
        const int jg = (b >> 1) & 127;
        const int j0 = jg * 16;
        const int ih = (b & 1) * 1024;       // i-half
        __shared__ float cjx[16], cjy[16], cjz[16];
        if (t < 16) {
            int gj = (bb*SEQ + j0 + t)*3;
            cjx[t] = ldin(coords, gj, isf);
            cjy[t] = ldin(coords, gj+1, isf);
            cjz[t] = ldin(coords, gj+2, isf);
        }
        __syncthreads();
        #pragma unroll
        for (int k = 0; k < 4; ++k) {
            int i = ih + k*256 + t;
            int gi = (bb*SEQ + i)*3;
            float px = ldin(coords, gi, isf), py = ldin(coords, gi+1, isf), pz = ldin(coords, gi+2, isf);
            short o[16];
            #pragma unroll
            for (int e = 0; e < 16; ++e) {
                float dx = px - cjx[e], dy = py - cjy[e], dz = pz - cjz[e];
                o[e] = f2b(sqrtf(dx*dx + dy*dy + dz*dz));
            }
            short* dst = dist8 + (((size_t)bb*128 + jg)*SEQ + i)*16;
            *(int4*)dst       = *(const int4*)(o);
            *(int4*)(dst + 8) = *(const int4*)(o + 8);
        }
    } else if (b < 1280) {
        size_t i = ((size_t)(b-512)*256 + t)*8;
        if (isf) {
            const float* xf = (const float*)x + i;
            short o[8];
            #pragma unroll
            for (int e = 0; e < 8; ++e) o[e] = f2b(xf[e]);
            *(int4*)(xb + i) = *(const int4*)o;
        } else {
            *(int4*)(xb + i) = *(const int4*)((const short*)x + i);
        }
    } else if (b < 1856) {
        int bb, NW; const void* W; short* WT;
        if (b < 1712) { bb = b - 1280; NW = QKVN; W = Wqkv; WT = WqT; }
        else          { bb = b - 1712; NW = DM;   W = Wout; WT = WoT; }
        int ntiles = NW >> 5;
        int kt = bb / ntiles, nt = bb % ntiles;
        int k0 = kt*32, n0 = nt*32;
        __shared__ float Ls[32][33];
        for (int idx = t; idx < 1024; idx += 256) {
            int r = idx >> 5, c = idx & 31;
            Ls[r][c] = ldin(W, (size_t)(k0+r)*NW + n0 + c, isf);
        }
        __syncthreads();
        for (int idx = t; idx < 1024; idx += 256) {
            int r2 = idx >> 5, c2 = idx & 31;
            WT[(size_t)(n0+r2)*DM + k0 + c2] = f2b(Ls[c2][r2]);
        }
    } else {
        int idx = (b - 1856)*256 + t;
        const float log2e = 1.4426950408889634f;
        if (idx < QKVN) bqf[idx] = ldin(bqkv, idx, isf);
        else if (idx < QKVN + DM) bof[idx - QKVN] = ldin(bout, idx - QKVN, isf);
        else if (idx < QKVN + DM + NH) wdf[idx - QKVN - DM] = ldin(Wdist, idx - QKVN - DM, isf)*log2e;
        else if (idx < QKVN + DM + 2*NH) bdf[idx - QKVN - DM - NH] = ldin(bdist, idx - QKVN - DM - NH, isf)*log2e;
    }
}

// ---------------- K1: MFMA GEMM qkv = xb @ Wqkv + b; scatter to 48-d frag-linear layouts
// qg2/kg2: [bh][tile16][ chunk0: (q)(L)(8)  | +512 chunk1: (q')(L)(4) ]  (768 shorts/tile)
// vg2:     [bh][tile16][dt(3)][(q)(L)(4)]                                (768 shorts/tile)
__global__ __launch_bounds__(256) void k_qkv(const short* __restrict__ xb,
    const short* __restrict__ WT, const float* __restrict__ bias,
    short* __restrict__ qg2, short* __restrict__ kg2, short* __restrict__ vg2)
{
    __shared__ __align__(16) short As[64*72];
    __shared__ __align__(16) short Bs[128*72];   // reused as epilogue buffer
    const int t = threadIdx.x;
    const int w = t >> 6, lane = t & 63, L = lane & 15, quad = lane >> 4;
    const int mt = blockIdx.x / 9, nt = blockIdx.x % 9;
    const int row0 = mt*64, col0 = nt*128;
    const int wm = w & 1, wn = w >> 1;
    float4v acc[2][4] = {};
    for (int k0 = 0; k0 < DM; k0 += 64) {
        __syncthreads();
        for (int c = t; c < 512; c += 256) {
            int row = c >> 3, k8 = c & 7;
            *(int4*)(&As[row*72 + k8*8]) = *(const int4*)(xb + (size_t)(row0+row)*DM + k0 + k8*8);
        }
        for (int c = t; c < 1024; c += 256) {
            int row = c >> 3, k8 = c & 7;
            *(int4*)(&Bs[row*72 + k8*8]) = *(const int4*)(WT + (size_t)(col0+row)*DM + k0 + k8*8);
        }
        __syncthreads();
        #pragma unroll
        for (int kc = 0; kc < 2; ++kc) {
            short8 a0 = *(const short8*)(&As[(32*wm + L)*72 + kc*32 + quad*8]);
            short8 a1 = *(const short8*)(&As[(32*wm + 16 + L)*72 + kc*32 + quad*8]);
            #pragma unroll
            for (int ni = 0; ni < 4; ++ni) {
                short8 bf = *(const short8*)(&Bs[(64*wn + 16*ni + L)*72 + kc*32 + quad*8]);
                acc[0][ni] = __builtin_amdgcn_mfma_f32_16x16x32_bf16(a0, bf, acc[0][ni], 0, 0, 0);
                acc[1][ni] = __builtin_amdgcn_mfma_f32_16x16x32_bf16(a1, bf, acc[1][ni], 0, 0, 0);
            }
        }
    }
    const int which = col0 / DM;     // uniform per block (0=q,1=k,2=v)
    const int cbase = col0 % DM;
    short* Ep = Bs;
    __syncthreads();
    if (which < 2) {
        // row-major Ep[64 tokens][136]
        #pragma unroll
        for (int mi = 0; mi < 2; ++mi)
            #pragma unroll
            for (int ni = 0; ni < 4; ++ni) {
                int col_l = 64*wn + 16*ni + L;
                float bv = bias[col0 + col_l];
                #pragma unroll
                for (int r = 0; r < 4; ++r) {
                    int row_l = 32*wm + 16*mi + quad*4 + r;
                    Ep[row_l*136 + col_l] = f2b(acc[mi][ni][r] + bv);
                }
            }
        __syncthreads();
        short* dst = which ? kg2 : qg2;
        for (int c = t; c < 1024; c += 256) {
            int row_l = c >> 4, col_l = (c & 15)*8;   // 8 consecutive d for one token
            int row_g = row0 + row_l;
            int bi = row_g >> 11, nn = row_g & (SEQ-1);
            int c2 = cbase + col_l;
            int hh = c2/HD, dh = c2%HD;
            int bh = bi*NH + hh;
            size_t base = ((size_t)bh*128 + (nn>>4))*768;
            int Ltok = nn & 15;
            const short* src = &Ep[row_l*136 + col_l];
            if (dh < 32) {
                *(int4*)(dst + base + (dh>>3)*128 + Ltok*8) = *(const int4*)src;
            } else {
                int q0 = (dh - 32) >> 2;
                *(int2*)(dst + base + 512 + q0*64     + Ltok*4) = *(const int2*)src;
                *(int2*)(dst + base + 512 + (q0+1)*64 + Ltok*4) = *(const int2*)(src + 4);
            }
        }
    } else {
        // col-major Ep[128 cols][72 tokens]
        #pragma unroll
        for (int mi = 0; mi < 2; ++mi)
            #pragma unroll
            for (int ni = 0; ni < 4; ++ni) {
                int col_l = 64*wn + 16*ni + L;
                float bv = bias[col0 + col_l];
                #pragma unroll
                for (int r = 0; r < 4; ++r) {
                    int row_l = 32*wm + 16*mi + quad*4 + r;
                    Ep[col_l*72 + row_l] = f2b(acc[mi][ni][r] + bv);
                }
            }
        __syncthreads();
        for (int c = t; c < 1024; c += 256) {
            int col_l = c >> 3, row8 = (c & 7)*8;     // 8 consecutive tokens, one d
            int row_g = row0 + row8;
            int bi = row_g >> 11, nn = row_g & (SEQ-1);
            int c2 = cbase + col_l;
            int hh = c2/HD, dh = c2%HD;
            int bh = bi*NH + hh;
            int dt = dh >> 4, Lh = dh & 15;
            size_t base3 = (((size_t)bh*128 + (nn>>4))*3 + dt)*256;
            int q0 = (nn & 15) >> 2;                  // nn multiple of 8 -> q0 in {0,2}
            const short* src = &Ep[col_l*72 + row8];
            *(int2*)(vg2 + base3 + q0*64     + Lh*4) = *(const int2*)src;
            *(int2*)(vg2 + base3 + (q0+1)*64 + Lh*4) = *(const int2*)(src + 4);
        }
    }
}

// ---------------- K2: flash attention; wave = 16 j-rows x 32 i; full j-range per block
// bid = it*16 + bh (XCD L2 locality). Register double-buffer on K + dist (i-tile-32
// budget: base ~70 VGPR + 24 acc + ~10 prefetch < 128 -> 4 waves/SIMD preserved by bounds).
__global__ __launch_bounds__(256, 4) void k_attn(
    const short* __restrict__ qg2, const short* __restrict__ kg2, const short* __restrict__ vg2,
    const short* __restrict__ dist8, const float* __restrict__ wdf,
    const float* __restrict__ bdf, short* __restrict__ aob)
{
    __shared__ float Ored[2][32*48];
    __shared__ float Lred[2][32];
    const int t = threadIdx.x;
    const int w = t >> 6, lane = t & 63, L = lane & 15, q = lane >> 4;
    const int bid = blockIdx.x;
    const int bh = bid & 15, it = bid >> 4;      // XCD-locality swizzle
    const int bi = bh >> 3, hh = bh & 7;
    const int i0 = it*32;
    const float scale2 = 0.14433756729740643f * 1.4426950408889634f;
    const float wd = wdf[hh], bd = bdf[hh];     // pre-scaled by log2e

    // Q fragments (held all loop): 2 i-tiles x (chunk0 b128 + chunk1 b64-zeroext)
    const short* qB = qg2 + ((size_t)bh*128 + it*2)*768;
    short8 qa0[2], qa1[2];
    #pragma unroll
    for (int nt = 0; nt < 2; ++nt) {
        qa0[nt] = *(const short8*)(qB + nt*768 + q*128 + L*8);
        qa1[nt] = s4z(*(const int2*)(qB + nt*768 + 512 + q*64 + L*4));
    }

    float4v accO[2][3] = {};
    float rsum[2] = {};

    const short* kBp = kg2 + ((size_t)bh*128 + w)*768;
    const short* vBp = vg2 + ((size_t)bh*128 + w)*768;
    const short* dBp = dist8 + (((size_t)bi*128 + w)*SEQ + i0 + L)*16 + 4*q;

    // register double-buffer: K chunk0 (short8), K chunk1 (int2), dist (2x int2)
    short8 kf[2];
    int2   kc1[2];
    int2   df[2][2];
    kf[0]    = *(const short8*)(kBp + q*128 + L*8);
    kc1[0]   = *(const int2*)(kBp + 512 + q*64 + L*4);
    df[0][0] = *(const int2*)(dBp);
    df[0][1] = *(const int2*)(dBp + 256);

    #pragma unroll 2
    for (int itr = 0; itr < SEQ/64; ++itr) {
        const int p = itr & 1;
        // prefetch next iteration's K + dist (wrap-to-self on last iter; uniform select)
        const short* kn = (itr + 1 < SEQ/64) ? kBp + 4*768 : kBp;
        const short* dn = (itr + 1 < SEQ/64) ? dBp + (size_t)4*SEQ*16 : dBp;
        kf[p^1]    = *(const short8*)(kn + q*128 + L*8);
        kc1[p^1]   = *(const int2*)(kn + 512 + q*64 + L*4);
        df[p^1][0] = *(const int2*)(dn);
        df[p^1][1] = *(const int2*)(dn + 256);
        // V loads for current iter (consumed after softmax)
        short8 vf[3];
        #pragma unroll
        for (int dt = 0; dt < 3; ++dt)
            vf[dt] = s4z(*(const int2*)(vBp + dt*256 + q*64 + L*4));
        // S^T = K Q^T
        short8 ka1 = s4z(kc1[p]);
        float4v sacc[2] = {};
        #pragma unroll
        for (int nt = 0; nt < 2; ++nt) {
            sacc[nt] = __builtin_amdgcn_mfma_f32_16x16x32_bf16(kf[p], qa0[nt], sacc[nt], 0, 0, 0);
            sacc[nt] = __builtin_amdgcn_mfma_f32_16x16x32_bf16(ka1,   qa1[nt], sacc[nt], 0, 0, 0);
        }
        short8 pa[2];
        #pragma unroll
        for (int nt = 0; nt < 2; ++nt) {
            int2 du = df[p][nt];
            float d0 = bflo((unsigned)du.x), d1 = bfhi((unsigned)du.x);
            float d2 = bflo((unsigned)du.y), d3 = bfhi((unsigned)du.y);
            float p0 = __builtin_amdgcn_exp2f(fmaf(sacc[nt][0], scale2, fmaf(d0, wd, bd)));
            float p1 = __builtin_amdgcn_exp2f(fmaf(sacc[nt][1], scale2, fmaf(d1, wd, bd)));
            float p2 = __builtin_amdgcn_exp2f(fmaf(sacc[nt][2], scale2, fmaf(d2, wd, bd)));
            float p3 = __builtin_amdgcn_exp2f(fmaf(sacc[nt][3], scale2, fmaf(d3, wd, bd)));
            rsum[nt] += (p0 + p1) + (p2 + p3);
            pa[nt] = u2z(pk2(p0, p1), pk2(p2, p3));
        }
        #pragma unroll
        for (int nt = 0; nt < 2; ++nt)
            #pragma unroll
            for (int dt = 0; dt < 3; ++dt)
                accO[nt][dt] = __builtin_amdgcn_mfma_f32_16x16x32_bf16(pa[nt], vf[dt], accO[nt][dt], 0, 0, 0);
        kBp += 4*768; vBp += 4*768; dBp += (size_t)4*SEQ*16;
    }
    // row-sums (over this wave's 16 j) -> all lanes hold sum for i = 16nt+L
    #pragma unroll
    for (int nt = 0; nt < 2; ++nt) {
        rsum[nt] += __shfl_xor(rsum[nt], 16);
        rsum[nt] += __shfl_xor(rsum[nt], 32);
    }
    // cross-wave tree reduction (4 waves -> Ored[0]/Lred[0])
    if (w >= 2) {
        float* Od = Ored[w-2];
        #pragma unroll
        for (int mt = 0; mt < 2; ++mt)
            #pragma unroll
            for (int dt = 0; dt < 3; ++dt)
                #pragma unroll
                for (int r = 0; r < 4; ++r)
                    Od[(16*mt + 4*q + r)*48 + 16*dt + L] = accO[mt][dt][r];
        if (q == 0)
            #pragma unroll
            for (int nt = 0; nt < 2; ++nt) Lred[w-2][16*nt + L] = rsum[nt];
    }
    __syncthreads();
    if (w < 2) {
        float* Od = Ored[w];
        #pragma unroll
        for (int mt = 0; mt < 2; ++mt)
            #pragma unroll
            for (int dt = 0; dt < 3; ++dt)
                #pragma unroll
                for (int r = 0; r < 4; ++r)
                    accO[mt][dt][r] += Od[(16*mt + 4*q + r)*48 + 16*dt + L];
        #pragma unroll
        for (int nt = 0; nt < 2; ++nt) rsum[nt] += Lred[w][16*nt + L];
    }
    __syncthreads();
    if (w == 1) {
        float* Od = Ored[0];
        #pragma unroll
        for (int mt = 0; mt < 2; ++mt)
            #pragma unroll
            for (int dt = 0; dt < 3; ++dt)
                #pragma unroll
                for (int r = 0; r < 4; ++r)
                    Od[(16*mt + 4*q + r)*48 + 16*dt + L] = accO[mt][dt][r];
        if (q == 0)
            #pragma unroll
            for (int nt = 0; nt < 2; ++nt) Lred[0][16*nt + L] = rsum[nt];
    }
    __syncthreads();
    if (w == 0) {
        float* Od = Ored[0];
        #pragma unroll
        for (int mt = 0; mt < 2; ++mt)
            #pragma unroll
            for (int dt = 0; dt < 3; ++dt)
                #pragma unroll
                for (int r = 0; r < 4; ++r)
                    Od[(16*mt + 4*q + r)*48 + 16*dt + L] += accO[mt][dt][r];
        if (q == 0)
            #pragma unroll
            for (int nt = 0; nt < 2; ++nt) Lred[0][16*nt + L] += rsum[nt];
    }
    __syncthreads();
    // all waves: normalize + coalesced int4 store of the 32x48 tile to aob
    for (int c = t; c < 192; c += 256) {
        int r = c / 6, d8 = (c % 6)*8;
        float inv = 1.0f / Lred[0][r];
        const float* src = &Ored[0][r*48 + d8];
        short o[8];
        #pragma unroll
        for (int e = 0; e < 8; ++e) o[e] = f2b(src[e]*inv);
        *(int4*)(aob + ((size_t)(bi*SEQ) + i0 + r)*DM + hh*HD + d8) = *(const int4*)o;
    }
}

// ---------------- K3: MFMA GEMM out = aob @ Wout + b_out
__global__ __launch_bounds__(256) void k_out(const short* __restrict__ aob,
    const short* __restrict__ WT, const float* __restrict__ bias,
    void* __restrict__ out, const void* __restrict__ x)
{
    __shared__ __align__(16) short As[64*72];
    __shared__ __align__(16) short Bs[128*72];
    const int isf = detect_isf(x);
    const int t = threadIdx.x;
    const int w = t >> 6, lane = t & 63, L = lane & 15, quad = lane >> 4;
    const int mt = blockIdx.x / 3, nt = blockIdx.x % 3;
    const int row0 = mt*64, col0 = nt*128;
    const int wm = w & 1, wn = w >> 1;
    float4v acc[2][4] = {};
    for (int k0 = 0; k0 < DM; k0 += 64) {
        __syncthreads();
        for (int c = t; c < 512; c += 256) {
            int row = c >> 3, k8 = c & 7;
            *(int4*)(&As[row*72 + k8*8]) = *(const int4*)(aob + (size_t)(row0+row)*DM + k0 + k8*8);
        }
        for (int c = t; c < 1024; c += 256) {
            int row = c >> 3, k8 = c & 7;
            *(int4*)(&Bs[row*72 + k8*8]) = *(const int4*)(WT + (size_t)(col0+row)*DM + k0 + k8*8);
        }
        __syncthreads();
        #pragma unroll
        for (int kc = 0; kc < 2; ++kc) {
            short8 a0 = *(const short8*)(&As[(32*wm + L)*72 + kc*32 + quad*8]);
            short8 a1 = *(const short8*)(&As[(32*wm + 16 + L)*72 + kc*32 + quad*8]);
            #pragma unroll
            for (int ni = 0; ni < 4; ++ni) {
                short8 bf = *(const short8*)(&Bs[(64*wn + 16*ni + L)*72 + kc*32 + quad*8]);
                acc[0][ni] = __builtin_amdgcn_mfma_f32_16x16x32_bf16(a0, bf, acc[0][ni], 0, 0, 0);
                acc[1][ni] = __builtin_amdgcn_mfma_f32_16x16x32_bf16(a1, bf, acc[1][ni], 0, 0, 0);
            }
        }
    }
    #pragma unroll
    for (int mi = 0; mi < 2; ++mi) {
        #pragma unroll
        for (int ni = 0; ni < 4; ++ni) {
            int col_g = col0 + 64*wn + 16*ni + L;
            float bv = bias[col_g];
            #pragma unroll
            for (int r = 0; r < 4; ++r) {
                int row_g = row0 + 32*wm + 16*mi + quad*4 + r;
                size_t oi = (size_t)row_g*DM + col_g;
                float val = acc[mi][ni][r] + bv;
                if (isf) ((float*)out)[oi] = val;
                else     ((bf16*)out)[oi]  = __float2bfloat16(val);
            }
        }
    }
}

extern "C" void kernel_launch(void* const* d_in, const int* in_sizes, int n_in,
                              void* d_out, int out_size, void* d_ws, size_t ws_size,
                              hipStream_t stream) {
    const void* x      = d_in[0];
    const void* coords = d_in[1];
    const void* Wqkv   = d_in[2];
    const void* bqkv   = d_in[3];
    const void* Wdist  = d_in[4];
    const void* bdist  = d_in[5];
    const void* Wout   = d_in[6];
    const void* bout   = d_in[7];

    short* qg2   = (short*)d_ws;                       // 16*128*768 = 1,572,864
    short* kg2   = qg2  + (size_t)1572864;
    short* vg2   = kg2  + (size_t)1572864;
    short* dist8 = vg2  + (size_t)1572864;             // 2*128*2048*16 = 8,388,608
    short* aob   = dist8 + (size_t)8388608;
    short* xb    = aob  + (size_t)1572864;
    short* WqT   = xb   + (size_t)1572864;
    short* WoT   = WqT  + (size_t)442368;
    float* bqf   = (float*)(WoT + (size_t)147456);
    float* bof   = bqf + QKVN;
    float* wdf   = bof + DM;
    float* bdf   = wdf + NH;

    k_prep<<<dim3(1863), dim3(256), 0, stream>>>(x, coords, Wqkv, Wout, bqkv, bout,
                                                 Wdist, bdist, dist8, xb, WqT, WoT,
                                                 bqf, bof, wdf, bdf);
    k_qkv<<<dim3(64*9), dim3(256), 0, stream>>>(xb, WqT, bqf, qg2, kg2, vg2);
    k_attn<<<dim3(16*64), dim3(256), 0, stream>>>(qg2, kg2, vg2, dist8, wdf, bdf, aob);
    k_out<<<dim3(64*3), dim3(256), 0, stream>>>(aob, WoT, bof, d_out, x);
}

// Round 15
// 149.635 us; speedup vs baseline: 1.0188x; 1.0188x over previous
//
#include <hip/hip_runtime.h>
#include <hip/hip_bf16.h>

#define NB 2
#define SEQ 2048
#define DM 384
#define NH 8
#define HD 48
#define QKVN 1152
#define BH (NB*NH)

typedef __hip_bfloat16 bf16;
typedef __attribute__((ext_vector_type(8))) short short8;
typedef __attribute__((ext_vector_type(4))) float float4v;

static __device__ __forceinline__ float bf2f(bf16 v){ return __bfloat162float(v); }
static __device__ __forceinline__ float ldin(const void* p, size_t i, int isf){
    return isf ? ((const float*)p)[i] : bf2f(((const bf16*)p)[i]);
}
// fp32 -> bf16 bits, RNE
static __device__ __forceinline__ short f2b(float f){
    union { float f; unsigned u; } a; a.f = f;
    unsigned r = a.u + 0x7FFFu + ((a.u >> 16) & 1u);
    return (short)(r >> 16);
}
// packed fp32x2 -> bf16x2 (v_cvt_pk_bf16_f32)
static __device__ __forceinline__ unsigned pk2(float a, float b){
    union { __hip_bfloat162 h; unsigned u; } r;
    r.h = __float22bfloat162_rn(float2{a, b});
    return r.u;
}
static __device__ __forceinline__ float bflo(unsigned u){
    union { unsigned u; float f; } a; a.u = u << 16; return a.f;
}
static __device__ __forceinline__ float bfhi(unsigned u){
    union { unsigned u; float f; } a; a.u = u & 0xFFFF0000u; return a.f;
}
// short4 (int2) -> short8 with zero upper half (k-relabel trick for d=48 / j=16 chunks)
static __device__ __forceinline__ short8 s4z(int2 v){
    union { int2 i; short s[4]; } u; u.i = v;
    short8 r = {u.s[0], u.s[1], u.s[2], u.s[3], 0, 0, 0, 0};
    return r;
}
static __device__ __forceinline__ short8 u2z(unsigned a, unsigned b){
    union { unsigned u[2]; short s[4]; } u0; u0.u[0] = a; u0.u[1] = b;
    short8 r = {u0.s[0], u0.s[1], u0.s[2], u0.s[3], 0, 0, 0, 0};
    return r;
}
// per-block input dtype probe (0 = bf16, 1 = fp32); wave-uniform
static __device__ __forceinline__ int detect_isf(const void* x){
    const unsigned short* xb = (const unsigned short*)x;
    int l = threadIdx.x & 63;
    union { unsigned u; float f; } a; a.u = ((unsigned)xb[2*l]) << 16;
    float ab = fabsf(a.f);
    int good = (a.f == 0.0f) || (ab > 9.765625e-4f && ab < 1024.0f);
    unsigned long long m = __ballot(good);
    return (__popcll(m) >= 32) ? 0 : 1;
}

// ---------------- K_prep
// sections: [0,512) dist (i-split x2) | [512,1280) xb | [1280,1712) WqT | [1712,1856) WoT | [1856,1863) misc
// dist8 layout: [b][jg(128)][i(2048)][16 jj] bf16
__global__ __launch_bounds__(256) void k_prep(const void* __restrict__ x,
    const void* __restrict__ coords,
    const void* __restrict__ Wqkv, const void* __restrict__ Wout,
    const void* __restrict__ bqkv, const void* __restrict__ bout,
    const void* __restrict__ Wdist, const void* __restrict__ bdist,
    short* __restrict__ dist8, short* __restrict__ xb,
    short* __restrict__ WqT, short* __restrict__ WoT,
    float* __restrict__ bqf, float* __restrict__ bof,
    float* __restrict__ wdf, float* __restrict__ bdf)
{
    const int isf = detect_isf(x);
    const int t = threadIdx.x;
    const int b = blockIdx.x;
    if (b < 512) {
        const int bb = b >> 8;               // batch
        const int jg = (b >> 1) & 127;
        const int j0 = jg * 16;
        const int ih = (b & 1) * 1024;       // i-half
        __shared__ float cjx[16], cjy[16], cjz[16];
        if (t < 16) {
            int gj = (bb*SEQ + j0 + t)*3;
            cjx[t] = ldin(coords, gj, isf);
            cjy[t] = ldin(coords, gj+1, isf);
            cjz[t] = ldin(coords, gj+2, isf);
        }
        __syncthreads();
        #pragma unroll
        for (int k = 0; k < 4; ++k) {
            int i = ih + k*256 + t;
            int gi = (bb*SEQ + i)*3;
            float px = ldin(coords, gi, isf), py = ldin(coords, gi+1, isf), pz = ldin(coords, gi+2, isf);
            short o[16];
            #pragma unroll
            for (int e = 0; e < 16; ++e) {
                float dx = px - cjx[e], dy = py - cjy[e], dz = pz - cjz[e];
                o[e] = f2b(sqrtf(dx*dx + dy*dy + dz*dz));
            }
            short* dst = dist8 + (((size_t)bb*128 + jg)*SEQ + i)*16;
            *(int4*)dst       = *(const int4*)(o);
            *(int4*)(dst + 8) = *(const int4*)(o + 8);
        }
    } else if (b < 1280) {
        size_t i = ((size_t)(b-512)*256 + t)*8;
        if (isf) {
            const float* xf = (const float*)x + i;
            short o[8];
            #pragma unroll
            for (int e = 0; e < 8; ++e) o[e] = f2b(xf[e]);
            *(int4*)(xb + i) = *(const int4*)o;
        } else {
            *(int4*)(xb + i) = *(const int4*)((const short*)x + i);
        }
    } else if (b < 1856) {
        int bb, NW; const void* W; short* WT;
        if (b < 1712) { bb = b - 1280; NW = QKVN; W = Wqkv; WT = WqT; }
        else          { bb = b - 1712; NW = DM;   W = Wout; WT = WoT; }
        int ntiles = NW >> 5;
        int kt = bb / ntiles, nt = bb % ntiles;
        int k0 = kt*32, n0 = nt*32;
        __shared__ float Ls[32][33];
        for (int idx = t; idx < 1024; idx += 256) {
            int r = idx >> 5, c = idx & 31;
            Ls[r][c] = ldin(W, (size_t)(k0+r)*NW + n0 + c, isf);
        }
        __syncthreads();
        for (int idx = t; idx < 1024; idx += 256) {
            int r2 = idx >> 5, c2 = idx & 31;
            WT[(size_t)(n0+r2)*DM + k0 + c2] = f2b(Ls[c2][r2]);
        }
    } else {
        int idx = (b - 1856)*256 + t;
        const float log2e = 1.4426950408889634f;
        if (idx < QKVN) bqf[idx] = ldin(bqkv, idx, isf);
        else if (idx < QKVN + DM) bof[idx - QKVN] = ldin(bout, idx - QKVN, isf);
        else if (idx < QKVN + DM + NH) wdf[idx - QKVN - DM] = ldin(Wdist, idx - QKVN - DM, isf)*log2e;
        else if (idx < QKVN + DM + 2*NH) bdf[idx - QKVN - DM - NH] = ldin(bdist, idx - QKVN - DM - NH, isf)*log2e;
    }
}

// ---------------- K1: MFMA GEMM qkv = xb @ Wqkv + b; scatter to 48-d frag-linear layouts
// qg2/kg2: [bh][tile16][ chunk0: (q)(L)(8)  | +512 chunk1: (q')(L)(4) ]  (768 shorts/tile)
// vg2:     [bh][tile16][dt(3)][(q)(L)(4)]                                (768 shorts/tile)
__global__ __launch_bounds__(256) void k_qkv(const short* __restrict__ xb,
    const short* __restrict__ WT, const float* __restrict__ bias,
    short* __restrict__ qg2, short* __restrict__ kg2, short* __restrict__ vg2)
{
    __shared__ __align__(16) short As[64*72];
    __shared__ __align__(16) short Bs[128*72];   // reused as epilogue buffer
    const int t = threadIdx.x;
    const int w = t >> 6, lane = t & 63, L = lane & 15, quad = lane >> 4;
    const int mt = blockIdx.x / 9, nt = blockIdx.x % 9;
    const int row0 = mt*64, col0 = nt*128;
    const int wm = w & 1, wn = w >> 1;
    float4v acc[2][4] = {};
    for (int k0 = 0; k0 < DM; k0 += 64) {
        __syncthreads();
        for (int c = t; c < 512; c += 256) {
            int row = c >> 3, k8 = c & 7;
            *(int4*)(&As[row*72 + k8*8]) = *(const int4*)(xb + (size_t)(row0+row)*DM + k0 + k8*8);
        }
        for (int c = t; c < 1024; c += 256) {
            int row = c >> 3, k8 = c & 7;
            *(int4*)(&Bs[row*72 + k8*8]) = *(const int4*)(WT + (size_t)(col0+row)*DM + k0 + k8*8);
        }
        __syncthreads();
        #pragma unroll
        for (int kc = 0; kc < 2; ++kc) {
            short8 a0 = *(const short8*)(&As[(32*wm + L)*72 + kc*32 + quad*8]);
            short8 a1 = *(const short8*)(&As[(32*wm + 16 + L)*72 + kc*32 + quad*8]);
            #pragma unroll
            for (int ni = 0; ni < 4; ++ni) {
                short8 bf = *(const short8*)(&Bs[(64*wn + 16*ni + L)*72 + kc*32 + quad*8]);
                acc[0][ni] = __builtin_amdgcn_mfma_f32_16x16x32_bf16(a0, bf, acc[0][ni], 0, 0, 0);
                acc[1][ni] = __builtin_amdgcn_mfma_f32_16x16x32_bf16(a1, bf, acc[1][ni], 0, 0, 0);
            }
        }
    }
    const int which = col0 / DM;     // uniform per block (0=q,1=k,2=v)
    const int cbase = col0 % DM;
    short* Ep = Bs;
    __syncthreads();
    if (which < 2) {
        // row-major Ep[64 tokens][136]
        #pragma unroll
        for (int mi = 0; mi < 2; ++mi)
            #pragma unroll
            for (int ni = 0; ni < 4; ++ni) {
                int col_l = 64*wn + 16*ni + L;
                float bv = bias[col0 + col_l];
                #pragma unroll
                for (int r = 0; r < 4; ++r) {
                    int row_l = 32*wm + 16*mi + quad*4 + r;
                    Ep[row_l*136 + col_l] = f2b(acc[mi][ni][r] + bv);
                }
            }
        __syncthreads();
        short* dst = which ? kg2 : qg2;
        for (int c = t; c < 1024; c += 256) {
            int row_l = c >> 4, col_l = (c & 15)*8;   // 8 consecutive d for one token
            int row_g = row0 + row_l;
            int bi = row_g >> 11, nn = row_g & (SEQ-1);
            int c2 = cbase + col_l;
            int hh = c2/HD, dh = c2%HD;
            int bh = bi*NH + hh;
            size_t base = ((size_t)bh*128 + (nn>>4))*768;
            int Ltok = nn & 15;
            const short* src = &Ep[row_l*136 + col_l];
            if (dh < 32) {
                *(int4*)(dst + base + (dh>>3)*128 + Ltok*8) = *(const int4*)src;
            } else {
                int q0 = (dh - 32) >> 2;
                *(int2*)(dst + base + 512 + q0*64     + Ltok*4) = *(const int2*)src;
                *(int2*)(dst + base + 512 + (q0+1)*64 + Ltok*4) = *(const int2*)(src + 4);
            }
        }
    } else {
        // col-major Ep[128 cols][72 tokens]
        #pragma unroll
        for (int mi = 0; mi < 2; ++mi)
            #pragma unroll
            for (int ni = 0; ni < 4; ++ni) {
                int col_l = 64*wn + 16*ni + L;
                float bv = bias[col0 + col_l];
                #pragma unroll
                for (int r = 0; r < 4; ++r) {
                    int row_l = 32*wm + 16*mi + quad*4 + r;
                    Ep[col_l*72 + row_l] = f2b(acc[mi][ni][r] + bv);
                }
            }
        __syncthreads();
        for (int c = t; c < 1024; c += 256) {
            int col_l = c >> 3, row8 = (c & 7)*8;     // 8 consecutive tokens, one d
            int row_g = row0 + row8;
            int bi = row_g >> 11, nn = row_g & (SEQ-1);
            int c2 = cbase + col_l;
            int hh = c2/HD, dh = c2%HD;
            int bh = bi*NH + hh;
            int dt = dh >> 4, Lh = dh & 15;
            size_t base3 = (((size_t)bh*128 + (nn>>4))*3 + dt)*256;
            int q0 = (nn & 15) >> 2;                  // nn multiple of 8 -> q0 in {0,2}
            const short* src = &Ep[col_l*72 + row8];
            *(int2*)(vg2 + base3 + q0*64     + Lh*4) = *(const int2*)src;
            *(int2*)(vg2 + base3 + (q0+1)*64 + Lh*4) = *(const int2*)(src + 4);
        }
    }
}

// ---------------- K2: flash attention; wave = 16 j-rows x 32 i; full j-range per block
// bid = it*16 + bh  (bh in low 4 bits -> all blocks of one bh land on XCD bh%8: K/V stay
// resident in that XCD's L2). Point-of-use loads — r6/r14 measured that manual register
// prefetch is neutral-to-negative here (compiler already hoists; no barriers in loop).
__global__ __launch_bounds__(256, 4) void k_attn(
    const short* __restrict__ qg2, const short* __restrict__ kg2, const short* __restrict__ vg2,
    const short* __restrict__ dist8, const float* __restrict__ wdf,
    const float* __restrict__ bdf, short* __restrict__ aob)
{
    __shared__ float Ored[2][32*48];
    __shared__ float Lred[2][32];
    const int t = threadIdx.x;
    const int w = t >> 6, lane = t & 63, L = lane & 15, q = lane >> 4;
    const int bid = blockIdx.x;
    const int bh = bid & 15, it = bid >> 4;      // XCD-locality swizzle
    const int bi = bh >> 3, hh = bh & 7;
    const int i0 = it*32;
    const float scale2 = 0.14433756729740643f * 1.4426950408889634f;
    const float wd = wdf[hh], bd = bdf[hh];     // pre-scaled by log2e

    // Q fragments (held all loop): 2 i-tiles x (chunk0 b128 + chunk1 b64-zeroext)
    const short* qB = qg2 + ((size_t)bh*128 + it*2)*768;
    short8 qa0[2], qa1[2];
    #pragma unroll
    for (int nt = 0; nt < 2; ++nt) {
        qa0[nt] = *(const short8*)(qB + nt*768 + q*128 + L*8);
        qa1[nt] = s4z(*(const int2*)(qB + nt*768 + 512 + q*64 + L*4));
    }

    float4v accO[2][3] = {};
    float rsum[2] = {};

    const short* kBp = kg2 + ((size_t)bh*128 + w)*768;
    const short* vBp = vg2 + ((size_t)bh*128 + w)*768;
    const short* dBp = dist8 + (((size_t)bi*128 + w)*SEQ + i0 + L)*16 + 4*q;

    #pragma unroll 2
    for (int itr = 0; itr < SEQ/64; ++itr) {
        short8 ka0 = *(const short8*)(kBp + q*128 + L*8);
        short8 ka1 = s4z(*(const int2*)(kBp + 512 + q*64 + L*4));
        float4v sacc[2] = {};
        #pragma unroll
        for (int nt = 0; nt < 2; ++nt) {
            sacc[nt] = __builtin_amdgcn_mfma_f32_16x16x32_bf16(ka0, qa0[nt], sacc[nt], 0, 0, 0);
            sacc[nt] = __builtin_amdgcn_mfma_f32_16x16x32_bf16(ka1, qa1[nt], sacc[nt], 0, 0, 0);
        }
        short8 vf[3];
        #pragma unroll
        for (int dt = 0; dt < 3; ++dt)
            vf[dt] = s4z(*(const int2*)(vBp + dt*256 + q*64 + L*4));
        short8 pa[2];
        #pragma unroll
        for (int nt = 0; nt < 2; ++nt) {
            int2 du = *(const int2*)(dBp + nt*256);
            float d0 = bflo((unsigned)du.x), d1 = bfhi((unsigned)du.x);
            float d2 = bflo((unsigned)du.y), d3 = bfhi((unsigned)du.y);
            float p0 = __builtin_amdgcn_exp2f(fmaf(sacc[nt][0], scale2, fmaf(d0, wd, bd)));
            float p1 = __builtin_amdgcn_exp2f(fmaf(sacc[nt][1], scale2, fmaf(d1, wd, bd)));
            float p2 = __builtin_amdgcn_exp2f(fmaf(sacc[nt][2], scale2, fmaf(d2, wd, bd)));
            float p3 = __builtin_amdgcn_exp2f(fmaf(sacc[nt][3], scale2, fmaf(d3, wd, bd)));
            rsum[nt] += (p0 + p1) + (p2 + p3);
            pa[nt] = u2z(pk2(p0, p1), pk2(p2, p3));
        }
        #pragma unroll
        for (int nt = 0; nt < 2; ++nt)
            #pragma unroll
            for (int dt = 0; dt < 3; ++dt)
                accO[nt][dt] = __builtin_amdgcn_mfma_f32_16x16x32_bf16(pa[nt], vf[dt], accO[nt][dt], 0, 0, 0);
        kBp += 4*768; vBp += 4*768; dBp += (size_t)4*SEQ*16;
    }
    // row-sums (over this wave's 16 j) -> all lanes hold sum for i = 16nt+L
    #pragma unroll
    for (int nt = 0; nt < 2; ++nt) {
        rsum[nt] += __shfl_xor(rsum[nt], 16);
        rsum[nt] += __shfl_xor(rsum[nt], 32);
    }
    // cross-wave tree reduction (4 waves -> Ored[0]/Lred[0])
    if (w >= 2) {
        float* Od = Ored[w-2];
        #pragma unroll
        for (int mt = 0; mt < 2; ++mt)
            #pragma unroll
            for (int dt = 0; dt < 3; ++dt)
                #pragma unroll
                for (int r = 0; r < 4; ++r)
                    Od[(16*mt + 4*q + r)*48 + 16*dt + L] = accO[mt][dt][r];
        if (q == 0)
            #pragma unroll
            for (int nt = 0; nt < 2; ++nt) Lred[w-2][16*nt + L] = rsum[nt];
    }
    __syncthreads();
    if (w < 2) {
        float* Od = Ored[w];
        #pragma unroll
        for (int mt = 0; mt < 2; ++mt)
            #pragma unroll
            for (int dt = 0; dt < 3; ++dt)
                #pragma unroll
                for (int r = 0; r < 4; ++r)
                    accO[mt][dt][r] += Od[(16*mt + 4*q + r)*48 + 16*dt + L];
        #pragma unroll
        for (int nt = 0; nt < 2; ++nt) rsum[nt] += Lred[w][16*nt + L];
    }
    __syncthreads();
    if (w == 1) {
        float* Od = Ored[0];
        #pragma unroll
        for (int mt = 0; mt < 2; ++mt)
            #pragma unroll
            for (int dt = 0; dt < 3; ++dt)
                #pragma unroll
                for (int r = 0; r < 4; ++r)
                    Od[(16*mt + 4*q + r)*48 + 16*dt + L] = accO[mt][dt][r];
        if (q == 0)
            #pragma unroll
            for (int nt = 0; nt < 2; ++nt) Lred[0][16*nt + L] = rsum[nt];
    }
    __syncthreads();
    if (w == 0) {
        float* Od = Ored[0];
        #pragma unroll
        for (int mt = 0; mt < 2; ++mt)
            #pragma unroll
            for (int dt = 0; dt < 3; ++dt)
                #pragma unroll
                for (int r = 0; r < 4; ++r)
                    Od[(16*mt + 4*q + r)*48 + 16*dt + L] += accO[mt][dt][r];
        if (q == 0)
            #pragma unroll
            for (int nt = 0; nt < 2; ++nt) Lred[0][16*nt + L] += rsum[nt];
    }
    __syncthreads();
    // all waves: normalize + coalesced int4 store of the 32x48 tile to aob
    for (int c = t; c < 192; c += 256) {
        int r = c / 6, d8 = (c % 6)*8;
        float inv = 1.0f / Lred[0][r];
        const float* src = &Ored[0][r*48 + d8];
        short o[8];
        #pragma unroll
        for (int e = 0; e < 8; ++e) o[e] = f2b(src[e]*inv);
        *(int4*)(aob + ((size_t)(bi*SEQ) + i0 + r)*DM + hh*HD + d8) = *(const int4*)o;
    }
}

// ---------------- K3: MFMA GEMM out = aob @ Wout + b_out
__global__ __launch_bounds__(256) void k_out(const short* __restrict__ aob,
    const short* __restrict__ WT, const float* __restrict__ bias,
    void* __restrict__ out, const void* __restrict__ x)
{
    __shared__ __align__(16) short As[64*72];
    __shared__ __align__(16) short Bs[128*72];
    const int isf = detect_isf(x);
    const int t = threadIdx.x;
    const int w = t >> 6, lane = t & 63, L = lane & 15, quad = lane >> 4;
    const int mt = blockIdx.x / 3, nt = blockIdx.x % 3;
    const int row0 = mt*64, col0 = nt*128;
    const int wm = w & 1, wn = w >> 1;
    float4v acc[2][4] = {};
    for (int k0 = 0; k0 < DM; k0 += 64) {
        __syncthreads();
        for (int c = t; c < 512; c += 256) {
            int row = c >> 3, k8 = c & 7;
            *(int4*)(&As[row*72 + k8*8]) = *(const int4*)(aob + (size_t)(row0+row)*DM + k0 + k8*8);
        }
        for (int c = t; c < 1024; c += 256) {
            int row = c >> 3, k8 = c & 7;
            *(int4*)(&Bs[row*72 + k8*8]) = *(const int4*)(WT + (size_t)(col0+row)*DM + k0 + k8*8);
        }
        __syncthreads();
        #pragma unroll
        for (int kc = 0; kc < 2; ++kc) {
            short8 a0 = *(const short8*)(&As[(32*wm + L)*72 + kc*32 + quad*8]);
            short8 a1 = *(const short8*)(&As[(32*wm + 16 + L)*72 + kc*32 + quad*8]);
            #pragma unroll
            for (int ni = 0; ni < 4; ++ni) {
                short8 bf = *(const short8*)(&Bs[(64*wn + 16*ni + L)*72 + kc*32 + quad*8]);
                acc[0][ni] = __builtin_amdgcn_mfma_f32_16x16x32_bf16(a0, bf, acc[0][ni], 0, 0, 0);
                acc[1][ni] = __builtin_amdgcn_mfma_f32_16x16x32_bf16(a1, bf, acc[1][ni], 0, 0, 0);
            }
        }
    }
    #pragma unroll
    for (int mi = 0; mi < 2; ++mi) {
        #pragma unroll
        for (int ni = 0; ni < 4; ++ni) {
            int col_g = col0 + 64*wn + 16*ni + L;
            float bv = bias[col_g];
            #pragma unroll
            for (int r = 0; r < 4; ++r) {
                int row_g = row0 + 32*wm + 16*mi + quad*4 + r;
                size_t oi = (size_t)row_g*DM + col_g;
                float val = acc[mi][ni][r] + bv;
                if (isf) ((float*)out)[oi] = val;
                else     ((bf16*)out)[oi]  = __float2bfloat16(val);
            }
        }
    }
}

extern "C" void kernel_launch(void* const* d_in, const int* in_sizes, int n_in,
                              void* d_out, int out_size, void* d_ws, size_t ws_size,
                              hipStream_t stream) {
    const void* x      = d_in[0];
    const void* coords = d_in[1];
    const void* Wqkv   = d_in[2];
    const void* bqkv   = d_in[3];
    const void* Wdist  = d_in[4];
    const void* bdist  = d_in[5];
    const void* Wout   = d_in[6];
    const void* bout   = d_in[7];

    short* qg2   = (short*)d_ws;                       // 16*128*768 = 1,572,864
    short* kg2   = qg2  + (size_t)1572864;
    short* vg2   = kg2  + (size_t)1572864;
    short* dist8 = vg2  + (size_t)1572864;             // 2*128*2048*16 = 8,388,608
    short* aob   = dist8 + (size_t)8388608;
    short* xb    = aob  + (size_t)1572864;
    short* WqT   = xb   + (size_t)1572864;
    short* WoT   = WqT  + (size_t)442368;
    float* bqf   = (float*)(WoT + (size_t)147456);
    float* bof   = bqf + QKVN;
    float* wdf   = bof + DM;
    float* bdf   = wdf + NH;

    k_prep<<<dim3(1863), dim3(256), 0, stream>>>(x, coords, Wqkv, Wout, bqkv, bout,
                                                 Wdist, bdist, dist8, xb, WqT, WoT,
                                                 bqf, bof, wdf, bdf);
    k_qkv<<<dim3(64*9), dim3(256), 0, stream>>>(xb, WqT, bqf, qg2, kg2, vg2);
    k_attn<<<dim3(16*64), dim3(256), 0, stream>>>(qg2, kg2, vg2, dist8, wdf, bdf, aob);
    k_out<<<dim3(64*3), dim3(256), 0, stream>>>(aob, WoT, bof, d_out, x);
}